// Round 1
// baseline (10032.138 us; speedup 1.0000x reference)
//
#include <hip/hip_runtime.h>
#include <hip/hip_bf16.h>
#include <math.h>

#define TT 1024
#define BB 64
#define IND 128
#define HID 512
#define OUTD 128

// Workspace layout (float offsets)
//  wih4 : [32][512][4]  packed W_ih^T (float4 along k)      @ 0        (65536 f)
//  whh4 : [128][512][4] packed W_hh^T (float4 along k)      @ 65536    (262144 f)
//  wfc4 : [128][128][4] packed W_fc^T (float4 along h)      @ 327680   (65536 f)
//  xp   : [T][B][HID] f32                                   @ 393216   (33554432 f)
//  r    : [T][B][HID] bf16 (ushort)                         @ 33947648 f (bytes: 67108864)
// total bytes = 202,899,456

__device__ __forceinline__ float bf2f(unsigned short u) {
    union { unsigned int i; float f; } v; v.i = ((unsigned int)u) << 16; return v.f;
}
__device__ __forceinline__ unsigned short f2bf(float f) {
    union { unsigned int i; float f; } v; v.f = f;
    unsigned int i = v.i;
    unsigned int r = (i + 0x7FFFu + ((i >> 16) & 1u)) >> 16;
    return (unsigned short)r;
}

// ---- prep: transpose + pack weights -------------------------------------
__global__ void k_prep(const float* __restrict__ wih, const float* __restrict__ whh,
                       const float* __restrict__ wfc, float* __restrict__ ws) {
    int fid = blockIdx.x * 256 + threadIdx.x;
    if (fid < 16384) {                       // W_ih: [512][128] -> [32][512] float4
        int k4 = fid >> 9, j = fid & 511;
        ((float4*)ws)[fid] = ((const float4*)wih)[j * 32 + k4];
    } else if (fid < 16384 + 65536) {        // W_hh: [512][512] -> [128][512] float4
        int f = fid - 16384;
        int k4 = f >> 9, j = f & 511;
        ((float4*)(ws + 65536))[f] = ((const float4*)whh)[j * 128 + k4];
    } else if (fid < 16384 + 65536 + 16384) { // W_fc: [128][512] -> [128][128] float4
        int f = fid - 81920;
        int h4 = f >> 7, o = f & 127;
        ((float4*)(ws + 327680))[f] = ((const float4*)wfc)[o * 128 + h4];
    }
}

// ---- phase 1: xp[t][b][j] = sum_k x[t,b,k] * W_ih[j,k] + b_ih[j] + b_hh[j]
__global__ __launch_bounds__(512) void k_xp(const float* __restrict__ x,
                                            const float* __restrict__ wih4,
                                            const float* __restrict__ bih,
                                            const float* __restrict__ bhh,
                                            float* __restrict__ xp) {
    int t = blockIdx.x, bg = blockIdx.y;      // bg: group of 16 batches
    int j = threadIdx.x;                      // 0..511
    __shared__ float4 xs[16 * 32];            // [16 b][32 k4]
    const float4* xsrc = (const float4*)(x + ((size_t)t * BB + bg * 16) * IND);
    xs[j] = xsrc[j];                          // exactly 512 float4
    __syncthreads();

    float bias = bih[j] + bhh[j];
    float acc[16];
#pragma unroll
    for (int b = 0; b < 16; b++) acc[b] = bias;

    const float4* wp = (const float4*)wih4;   // [32][512]
#pragma unroll 4
    for (int k4 = 0; k4 < 32; k4++) {
        float4 w = wp[k4 * 512 + j];
#pragma unroll
        for (int b = 0; b < 16; b++) {
            float4 xv = xs[b * 32 + k4];
            acc[b] += w.x * xv.x + w.y * xv.y + w.z * xv.z + w.w * xv.w;
        }
    }
    float* dst = xp + ((size_t)t * BB + bg * 16) * HID + j;
#pragma unroll
    for (int b = 0; b < 16; b++) dst[(size_t)b * HID] = acc[b];
}

// ---- phase 2: recurrence, one block per batch ---------------------------
__global__ __launch_bounds__(512) void k_rnn(const float* __restrict__ xp,
                                             const float* __restrict__ whh4,
                                             const float* __restrict__ h0,
                                             unsigned short* __restrict__ r,
                                             float* __restrict__ out) {
    int b = blockIdx.x;
    int j = threadIdx.x;
    __shared__ float4 hs[128];                // h as 128 float4
    if (j < 128) hs[j] = ((const float4*)(h0 + (size_t)b * HID))[j];
    __syncthreads();

    const float4* wp = (const float4*)whh4;   // [128][512]
    const float* xpb = xp + (size_t)b * HID + j;
    unsigned short* rb = r + (size_t)b * HID + j;

    float hn = 0.f;
    for (int t = 0; t < TT; t++) {
        float x0 = xpb[(size_t)t * BB * HID];
        float4 a = {0.f, 0.f, 0.f, 0.f};
#pragma unroll 16
        for (int k4 = 0; k4 < 128; k4++) {
            float4 w = wp[k4 * 512 + j];
            float4 hv = hs[k4];
            a.x += w.x * hv.x;
            a.y += w.y * hv.y;
            a.z += w.z * hv.z;
            a.w += w.w * hv.w;
        }
        hn = tanhf(x0 + (a.x + a.y) + (a.z + a.w));
        __syncthreads();                      // all reads of hs done
        ((float*)hs)[j] = hn;
        rb[(size_t)t * BB * HID] = f2bf(hn);
        __syncthreads();                      // hs updated for next step
    }
    out[8388608 + (size_t)b * HID + j] = hn;  // h_last (fp32, last step)
}

// ---- phase 3: y[t][b][o] = sum_h r[t,b,h] * W_fc[o,h] + b_fc[o] ---------
__global__ __launch_bounds__(512) void k_y(const unsigned short* __restrict__ r,
                                           const float* __restrict__ wfc4,
                                           const float* __restrict__ bfc,
                                           float* __restrict__ y) {
    int t = blockIdx.x, bg = blockIdx.y;
    int tid = threadIdx.x;
    int o = tid & 127, bq = tid >> 7;         // bq: 0..3, each handles 4 batches
    __shared__ float rs[16 * 512];            // 32 KiB
    const unsigned short* rsrc = r + ((size_t)t * BB + bg * 16) * HID;
    for (int i = tid; i < 16 * 512 / 2; i += 512) {
        ushort2 u = ((const ushort2*)rsrc)[i];
        rs[2 * i] = bf2f(u.x);
        rs[2 * i + 1] = bf2f(u.y);
    }
    __syncthreads();

    float acc[4] = {0.f, 0.f, 0.f, 0.f};
    const float4* wp = (const float4*)wfc4;   // [128][128]
    const float4* rs4 = (const float4*)rs;    // [16][128]
#pragma unroll 4
    for (int h4 = 0; h4 < 128; h4++) {
        float4 w = wp[h4 * 128 + o];
#pragma unroll
        for (int bb = 0; bb < 4; bb++) {
            float4 rv = rs4[(bq * 4 + bb) * 128 + h4];
            acc[bb] += w.x * rv.x + w.y * rv.y + w.z * rv.z + w.w * rv.w;
        }
    }
    float bias = bfc[o];
    float* dst = y + ((size_t)t * BB + bg * 16 + bq * 4) * OUTD + o;
#pragma unroll
    for (int bb = 0; bb < 4; bb++) dst[(size_t)bb * OUTD] = acc[bb] + bias;
}

extern "C" void kernel_launch(void* const* d_in, const int* in_sizes, int n_in,
                              void* d_out, int out_size, void* d_ws, size_t ws_size,
                              hipStream_t stream) {
    (void)in_sizes; (void)n_in; (void)out_size; (void)ws_size;
    const float* x    = (const float*)d_in[0];
    const float* h0   = (const float*)d_in[1];
    const float* wih  = (const float*)d_in[2];
    const float* whh  = (const float*)d_in[3];
    const float* bih  = (const float*)d_in[4];
    const float* bhh  = (const float*)d_in[5];
    const float* wfc  = (const float*)d_in[6];
    const float* bfc  = (const float*)d_in[7];
    float* out = (float*)d_out;

    float* ws = (float*)d_ws;
    float* wih4 = ws;
    float* whh4 = ws + 65536;
    float* wfc4 = ws + 327680;
    float* xp   = ws + 393216;
    unsigned short* rbuf = (unsigned short*)(ws + 393216 + 33554432);

    hipLaunchKernelGGL(k_prep, dim3(384), dim3(256), 0, stream, wih, whh, wfc, ws);
    hipLaunchKernelGGL(k_xp, dim3(TT, BB / 16), dim3(512), 0, stream, x, wih4, bih, bhh, xp);
    hipLaunchKernelGGL(k_rnn, dim3(BB), dim3(512), 0, stream, xp, whh4, h0, rbuf, out);
    hipLaunchKernelGGL(k_y, dim3(TT, BB / 16), dim3(512), 0, stream, rbuf, wfc4, bfc, out);
}

// Round 3
// 6081.925 us; speedup vs baseline: 1.6495x; 1.6495x over previous
//
#include <hip/hip_runtime.h>
#include <hip/hip_bf16.h>
#include <math.h>

#define TT 1024
#define BB 64
#define IND 128
#define HID 512
#define OUTD 128

// Workspace layout (float offsets):
//  wih4 : [32][512][4]  packed W_ih^T (float4 along k)   @ 0          (65536 f)
//  wfc4 : [128][128][4] packed W_fc^T (float4 along h)   @ 65536      (65536 f)
//  xp   : [T][B][HID] f32                                @ 131072     (33554432 f)
//  r    : [T][B][HID] bf16                               @ 33685504 f (16777216 f worth)
//  hbuf : [2][B][HID] f32 (double-buffered h exchange)   @ 50462720   (65536 f)
//  cnt  : [B][32] u32 (per-batch step counters, padded)  @ 50528256   (2048 f)

#define WIH4_OFF 0
#define WFC4_OFF 65536
#define XP_OFF   131072
#define R_OFF    33685504
#define HBUF_OFF 50462720
#define CNT_OFF  50528256

__device__ __forceinline__ float bf2f(unsigned short u) {
    union { unsigned int i; float f; } v; v.i = ((unsigned int)u) << 16; return v.f;
}
__device__ __forceinline__ unsigned short f2bf(float f) {
    union { unsigned int i; float f; } v; v.f = f;
    unsigned int i = v.i;
    unsigned int r = (i + 0x7FFFu + ((i >> 16) & 1u)) >> 16;
    return (unsigned short)r;
}

// ---- prep: transpose + pack W_ih, W_fc ----------------------------------
__global__ void k_prep(const float* __restrict__ wih, const float* __restrict__ wfc,
                       float* __restrict__ ws) {
    int fid = blockIdx.x * 256 + threadIdx.x;
    if (fid < 16384) {                        // W_ih: [512][128] -> [32][512] float4
        int k4 = fid >> 9, j = fid & 511;
        ((float4*)(ws + WIH4_OFF))[fid] = ((const float4*)wih)[j * 32 + k4];
    } else if (fid < 32768) {                 // W_fc: [128][512] -> [128][128] float4
        int f = fid - 16384;
        int h4 = f >> 7, o = f & 127;
        ((float4*)(ws + WFC4_OFF))[f] = ((const float4*)wfc)[o * 128 + h4];
    }
}

// ---- phase 1: xp[t][b][j] = x[t,b,:] . W_ih[j,:] + b_ih[j] + b_hh[j] ----
__global__ __launch_bounds__(512) void k_xp(const float* __restrict__ x,
                                            const float* __restrict__ wih4,
                                            const float* __restrict__ bih,
                                            const float* __restrict__ bhh,
                                            float* __restrict__ xp) {
    int t = blockIdx.x, bg = blockIdx.y;      // bg: group of 16 batches
    int j = threadIdx.x;                      // 0..511
    __shared__ float4 xs[16 * 32];            // [16 b][32 k4]
    const float4* xsrc = (const float4*)(x + ((size_t)t * BB + bg * 16) * IND);
    xs[j] = xsrc[j];
    __syncthreads();

    float bias = bih[j] + bhh[j];
    float acc[16];
#pragma unroll
    for (int b = 0; b < 16; b++) acc[b] = bias;

    const float4* wp = (const float4*)wih4;   // [32][512]
#pragma unroll 4
    for (int k4 = 0; k4 < 32; k4++) {
        float4 w = wp[k4 * 512 + j];
#pragma unroll
        for (int b = 0; b < 16; b++) {
            float4 xv = xs[b * 32 + k4];
            acc[b] += w.x * xv.x + w.y * xv.y + w.z * xv.z + w.w * xv.w;
        }
    }
    float* dst = xp + ((size_t)t * BB + bg * 16) * HID + j;
#pragma unroll
    for (int b = 0; b < 16; b++) dst[(size_t)b * HID] = acc[b];
}

// ---- phase 2: persistent-weight recurrence ------------------------------
// Grid: 256 blocks = 64 batches x 4 j-groups. One block per CU, W_hh slice
// register-resident (128 rows x 512 cols / block = 128 VGPRs/thread).
// Cross-block h exchange per step: agent-scope stores to hbuf[par] + one
// release-counter per batch; double-buffer parity makes WAR safe.
__global__ __launch_bounds__(512, 2) void k_rnn(const float* __restrict__ xp,
                                                const float* __restrict__ whh,
                                                unsigned short* __restrict__ r,
                                                float* __restrict__ out,
                                                float* __restrict__ hbuf,
                                                unsigned int* __restrict__ cnt) {
    const int b = blockIdx.x & 63;
    const int g = blockIdx.x >> 6;
    const int tid = threadIdx.x;
    const int kt = tid >> 5;                  // 0..15  (k-slice of 32)
    const int jg = tid & 31;                  // 0..31  (j-group of 4)
    const int jbase = g * 128;

    // Register-resident W_hh slice: rows jbase+jg*4+{0..3}, cols kt*32..kt*32+31
    float4 wreg[4][8];
    const float4* wsrc = (const float4*)whh;  // [512][128] float4 view
#pragma unroll
    for (int j4 = 0; j4 < 4; j4++)
#pragma unroll
        for (int i4 = 0; i4 < 8; i4++)
            wreg[j4][i4] = wsrc[(size_t)(jbase + jg * 4 + j4) * 128 + kt * 8 + i4];

    __shared__ float4 hs4[128];               // h_t for this batch (512 f)
    __shared__ float pbuf[16][128];           // partial sums [kt][j]

    // initial h_0 (hbuf parity 0, written by async memcpy before this kernel)
    {
        float v = __hip_atomic_load(hbuf + (size_t)b * HID + tid,
                                    __ATOMIC_RELAXED, __HIP_MEMORY_SCOPE_AGENT);
        ((float*)hs4)[tid] = v;
    }
    __syncthreads();

    const float* xpb = xp + (size_t)b * HID + jbase;
    unsigned short* rb = r + (size_t)b * HID + jbase;
    unsigned int* cb = cnt + b * 32;

    float xpv = (tid < 128) ? xpb[tid] : 0.f;
    float hn = 0.f;

    for (int t = 0; t < TT; t++) {
        // --- partial GEMV from registers ---
        float4 a0 = {0,0,0,0}, a1 = {0,0,0,0}, a2 = {0,0,0,0}, a3 = {0,0,0,0};
#pragma unroll
        for (int i4 = 0; i4 < 8; i4++) {
            float4 hv = hs4[kt * 8 + i4];
            a0.x += wreg[0][i4].x * hv.x; a0.y += wreg[0][i4].y * hv.y;
            a0.z += wreg[0][i4].z * hv.z; a0.w += wreg[0][i4].w * hv.w;
            a1.x += wreg[1][i4].x * hv.x; a1.y += wreg[1][i4].y * hv.y;
            a1.z += wreg[1][i4].z * hv.z; a1.w += wreg[1][i4].w * hv.w;
            a2.x += wreg[2][i4].x * hv.x; a2.y += wreg[2][i4].y * hv.y;
            a2.z += wreg[2][i4].z * hv.z; a2.w += wreg[2][i4].w * hv.w;
            a3.x += wreg[3][i4].x * hv.x; a3.y += wreg[3][i4].y * hv.y;
            a3.z += wreg[3][i4].z * hv.z; a3.w += wreg[3][i4].w * hv.w;
        }
        *(float4*)&pbuf[kt][jg * 4] = make_float4(
            (a0.x + a0.y) + (a0.z + a0.w), (a1.x + a1.y) + (a1.z + a1.w),
            (a2.x + a2.y) + (a2.z + a2.w), (a3.x + a3.y) + (a3.z + a3.w));
        __syncthreads();

        const int par1 = (t + 1) & 1;
        if (tid < 128) {
            float s = xpv;
#pragma unroll
            for (int k2 = 0; k2 < 16; k2++) s += pbuf[k2][tid];
            hn = tanhf(s);
            rb[(size_t)t * BB * HID + tid] = f2bf(hn);
            __hip_atomic_store(hbuf + (size_t)par1 * BB * HID + (size_t)b * HID + jbase + tid,
                               hn, __ATOMIC_RELAXED, __HIP_MEMORY_SCOPE_AGENT);
        }
        __syncthreads();                      // drains vmem: h slice globally visible

        // prefetch next xp (in flight across the spin)
        if (tid < 128 && t + 1 < TT) xpv = xpb[(size_t)(t + 1) * BB * HID + tid];

        if (tid == 0) {
            __hip_atomic_fetch_add(cb, 1u, __ATOMIC_RELEASE, __HIP_MEMORY_SCOPE_AGENT);
            unsigned int target = 4u * (unsigned)(t + 1);
            long polls = 0;
            long lim = (t == 0) ? (1L << 22) : (1L << 17);  // watchdog: fail loud, not hung
            while (__hip_atomic_load(cb, __ATOMIC_ACQUIRE, __HIP_MEMORY_SCOPE_AGENT) < target) {
                if (++polls > lim) break;
            }
        }
        __syncthreads();

        // fetch full h_{t+1}
        {
            float v = __hip_atomic_load(hbuf + (size_t)par1 * BB * HID + (size_t)b * HID + tid,
                                        __ATOMIC_RELAXED, __HIP_MEMORY_SCOPE_AGENT);
            ((float*)hs4)[tid] = v;
        }
        __syncthreads();
    }

    if (tid < 128)
        out[(size_t)TT * BB * OUTD + (size_t)b * HID + jbase + tid] = hn;
}

// ---- phase 3: y[t][b][o] = r[t,b,:] . W_fc[o,:] + b_fc[o] ---------------
__global__ __launch_bounds__(512) void k_y(const unsigned short* __restrict__ r,
                                           const float* __restrict__ wfc4,
                                           const float* __restrict__ bfc,
                                           float* __restrict__ y) {
    int t = blockIdx.x, bg = blockIdx.y;
    int tid = threadIdx.x;
    int o = tid & 127, bq = tid >> 7;
    __shared__ float rs[16 * 512];
    const unsigned short* rsrc = r + ((size_t)t * BB + bg * 16) * HID;
    for (int i = tid; i < 16 * 512 / 2; i += 512) {
        ushort2 u = ((const ushort2*)rsrc)[i];
        rs[2 * i] = bf2f(u.x);
        rs[2 * i + 1] = bf2f(u.y);
    }
    __syncthreads();

    float acc[4] = {0.f, 0.f, 0.f, 0.f};
    const float4* wp = (const float4*)wfc4;
    const float4* rs4 = (const float4*)rs;
#pragma unroll 4
    for (int h4 = 0; h4 < 128; h4++) {
        float4 w = wp[h4 * 128 + o];
#pragma unroll
        for (int bb = 0; bb < 4; bb++) {
            float4 rv = rs4[(bq * 4 + bb) * 128 + h4];
            acc[bb] += w.x * rv.x + w.y * rv.y + w.z * rv.z + w.w * rv.w;
        }
    }
    float bias = bfc[o];
    float* dst = y + ((size_t)t * BB + bg * 16 + bq * 4) * OUTD + o;
#pragma unroll
    for (int bb = 0; bb < 4; bb++) dst[(size_t)bb * OUTD] = acc[bb] + bias;
}

extern "C" void kernel_launch(void* const* d_in, const int* in_sizes, int n_in,
                              void* d_out, int out_size, void* d_ws, size_t ws_size,
                              hipStream_t stream) {
    (void)in_sizes; (void)n_in; (void)out_size; (void)ws_size;
    const float* x    = (const float*)d_in[0];
    const float* h0   = (const float*)d_in[1];
    const float* wih  = (const float*)d_in[2];
    const float* whh  = (const float*)d_in[3];
    const float* bih  = (const float*)d_in[4];
    const float* bhh  = (const float*)d_in[5];
    const float* wfc  = (const float*)d_in[6];
    const float* bfc  = (const float*)d_in[7];
    float* out = (float*)d_out;

    float* ws = (float*)d_ws;
    float* wih4 = ws + WIH4_OFF;
    float* wfc4 = ws + WFC4_OFF;
    float* xp   = ws + XP_OFF;
    unsigned short* rbuf = (unsigned short*)(ws + R_OFF);
    float* hbuf = ws + HBUF_OFF;
    unsigned int* cnt = (unsigned int*)(ws + CNT_OFF);

    hipMemsetAsync(cnt, 0, 64 * 32 * sizeof(unsigned int), stream);
    hipMemcpyAsync(hbuf, h0, (size_t)BB * HID * sizeof(float),
                   hipMemcpyDeviceToDevice, stream);
    hipLaunchKernelGGL(k_prep, dim3(128), dim3(256), 0, stream, wih, wfc, ws);
    hipLaunchKernelGGL(k_xp, dim3(TT, BB / 16), dim3(512), 0, stream, x, wih4, bih, bhh, xp);
    hipLaunchKernelGGL(k_rnn, dim3(256), dim3(512), 0, stream, xp, whh, rbuf, out, hbuf, cnt);
    hipLaunchKernelGGL(k_y, dim3(TT, BB / 16), dim3(512), 0, stream, rbuf, wfc4, bfc, out);
}